// Round 1
// baseline (67.704 us; speedup 1.0000x reference)
//
#include <hip/hip_runtime.h>

#define B_SZ 32
#define T_PH 512
#define H_DIM 256
#define N_EDGES 255
#define MAX_LEN 4096

// ---------------- Kernel A: per-row inclusive cumsum of durations ----------------
__global__ void scan_kernel(const int* __restrict__ dur,
                            int* __restrict__ csum,
                            float* __restrict__ mel_out) {
    const int b = blockIdx.x;
    const int tid = threadIdx.x;
    __shared__ int s[T_PH];
    s[tid] = dur[b * T_PH + tid];
    __syncthreads();
#pragma unroll
    for (int off = 1; off < T_PH; off <<= 1) {
        int v = (tid >= off) ? s[tid - off] : 0;
        __syncthreads();
        s[tid] += v;
        __syncthreads();
    }
    csum[b * T_PH + tid] = s[tid];
    if (tid == T_PH - 1) {
        mel_out[b] = (float)s[T_PH - 1];  // mel_len as f32 (exact for < 2^24)
    }
}

// searchsorted(bins, v) side='left': first i with bins[i] >= v
__device__ __forceinline__ int bisect_left(const float* __restrict__ bins, float v) {
    int lo = 0, hi = N_EDGES;
    while (lo < hi) {
        int mid = (lo + hi) >> 1;
        if (bins[mid] < v) lo = mid + 1; else hi = mid;
    }
    return lo;  // in [0, 255]
}

// ---------------- Kernel B: length-regulate + variance embedding add ----------------
// 4 frames per 256-thread block; 64 lanes per frame; float4 per lane (H=256 = 64 x float4)
__global__ void expand_kernel(const float* __restrict__ x,
                              const float* __restrict__ pt,
                              const float* __restrict__ et,
                              const float* __restrict__ pbins,
                              const float* __restrict__ ebins,
                              const float* __restrict__ pemb,
                              const float* __restrict__ eemb,
                              const int* __restrict__ csum,
                              float* __restrict__ out) {
    const int sub   = threadIdx.x >> 6;          // frame within block, 0..3
    const int lane4 = threadIdx.x & 63;          // float4 index within frame
    const int frame = blockIdx.x * 4 + sub;      // global frame over B*MAX_LEN
    const int b = frame >> 12;                   // / MAX_LEN
    const int t = frame & (MAX_LEN - 1);

    const int* cs = csum + b * T_PH;
    const int mel = cs[T_PH - 1];

    float4 val = make_float4(0.f, 0.f, 0.f, 0.f);
    if (t < mel) {
        // searchsorted(csum, t, side='right'): first i with cs[i] > t
        int lo = 0, hi = T_PH;
        while (lo < hi) {
            int mid = (lo + hi) >> 1;
            if (cs[mid] > t) hi = mid; else lo = mid + 1;
        }
        int ph = lo < (T_PH - 1) ? lo : (T_PH - 1);

        const float pv = pt[b * T_PH + ph];
        const float ev = et[b * T_PH + ph];
        const int pi = bisect_left(pbins, pv);
        const int ei = bisect_left(ebins, ev);

        const float4* xr = (const float4*)(x + (size_t)(b * T_PH + ph) * H_DIM);
        const float4* pr = (const float4*)(pemb + (size_t)pi * H_DIM);
        const float4* er = (const float4*)(eemb + (size_t)ei * H_DIM);
        const float4 a = xr[lane4];
        const float4 p = pr[lane4];
        const float4 e = er[lane4];
        val.x = a.x + p.x + e.x;
        val.y = a.y + p.y + e.y;
        val.z = a.z + p.z + e.z;
        val.w = a.w + p.w + e.w;
    }
    ((float4*)out)[(size_t)frame * 64 + lane4] = val;
}

extern "C" void kernel_launch(void* const* d_in, const int* in_sizes, int n_in,
                              void* d_out, int out_size, void* d_ws, size_t ws_size,
                              hipStream_t stream) {
    const float* x     = (const float*)d_in[0];
    const float* pt    = (const float*)d_in[1];
    const float* et    = (const float*)d_in[2];
    const float* pbins = (const float*)d_in[3];
    const float* ebins = (const float*)d_in[4];
    const float* pemb  = (const float*)d_in[5];
    const float* eemb  = (const float*)d_in[6];
    const int*   dur   = (const int*)d_in[7];
    // d_in[8] = max_len scalar (compile-time constant here)

    float* out = (float*)d_out;                          // 32*4096*256 floats
    float* mel_out = out + (size_t)B_SZ * MAX_LEN * H_DIM; // 32 floats (tuple tail)
    int* csum = (int*)d_ws;                              // 32*512 ints

    scan_kernel<<<B_SZ, T_PH, 0, stream>>>(dur, csum, mel_out);

    const int frames = B_SZ * MAX_LEN;                   // 131072
    expand_kernel<<<frames / 4, 256, 0, stream>>>(x, pt, et, pbins, ebins,
                                                  pemb, eemb, csum, out);
}

// Round 2
// 34.512 us; speedup vs baseline: 1.9617x; 1.9617x over previous
//
#include <hip/hip_runtime.h>

#define B_SZ 32
#define T_PH 512
#define H_DIM 256
#define N_EDGES 255
#define MAX_LEN 4096

// ---------------- Kernel A: scan + scatter ph_idx + bin bisects (all searches here) ----
__global__ void prep_kernel(const int* __restrict__ dur,
                            const float* __restrict__ pt,
                            const float* __restrict__ et,
                            const float* __restrict__ pbins,
                            const float* __restrict__ ebins,
                            int* __restrict__ pack_idx,   // B*T_PH: pi | (ei<<16)
                            int* __restrict__ ph_idx,     // B*MAX_LEN: phoneme or -1
                            float* __restrict__ mel_out) {
    const int b = blockIdx.x;
    const int tid = threadIdx.x;
    __shared__ int s[T_PH];
    __shared__ float pb[N_EDGES];
    __shared__ float eb[N_EDGES];

    if (tid < N_EDGES) pb[tid] = pbins[tid];
    else if (tid >= 256 && tid < 256 + N_EDGES) eb[tid - 256] = ebins[tid - 256];

    const int d = dur[b * T_PH + tid];
    s[tid] = d;
    __syncthreads();
#pragma unroll
    for (int off = 1; off < T_PH; off <<= 1) {
        int v = (tid >= off) ? s[tid - off] : 0;
        __syncthreads();
        s[tid] += v;
        __syncthreads();
    }
    const int end   = s[tid];
    const int start = end - d;
    const int mel   = s[T_PH - 1];

    // per-phoneme bin bisects (side='left'), bins in LDS
    const float pv = pt[b * T_PH + tid];
    const float ev = et[b * T_PH + tid];
    int lo = 0, hi = N_EDGES;
    while (lo < hi) { int m = (lo + hi) >> 1; if (pb[m] < pv) lo = m + 1; else hi = m; }
    const int pi = lo;
    lo = 0; hi = N_EDGES;
    while (lo < hi) { int m = (lo + hi) >> 1; if (eb[m] < ev) lo = m + 1; else hi = m; }
    const int ei = lo;
    pack_idx[b * T_PH + tid] = pi | (ei << 16);

    // scatter ph_idx: equivalent to searchsorted(csum, t, side='right')
    int* pr = ph_idx + (size_t)b * MAX_LEN;
    for (int t = start; t < end; ++t) pr[t] = tid;
    for (int t = mel + tid; t < MAX_LEN; t += T_PH) pr[t] = -1;

    if (tid == T_PH - 1) mel_out[b] = (float)mel;  // exact for < 2^24
}

// ---------------- Kernel B: pure gather + add, write-BW bound ----------------
// 4 frames/block, 64 lanes/frame, float4 per lane
__global__ void expand_kernel(const float* __restrict__ x,
                              const float* __restrict__ pemb,
                              const float* __restrict__ eemb,
                              const int* __restrict__ pack_idx,
                              const int* __restrict__ ph_idx,
                              float* __restrict__ out) {
    const int sub   = threadIdx.x >> 6;
    const int lane4 = threadIdx.x & 63;
    const int frame = blockIdx.x * 4 + sub;
    const int b = frame >> 12;

    const int ph = ph_idx[frame];            // broadcast within wave
    float4 val = make_float4(0.f, 0.f, 0.f, 0.f);
    if (ph >= 0) {
        const int pk = pack_idx[b * T_PH + ph];  // broadcast
        const int pi = pk & 0xffff;
        const int ei = pk >> 16;
        const float4* xr = (const float4*)(x + (size_t)(b * T_PH + ph) * H_DIM);
        const float4* pr = (const float4*)(pemb + (size_t)pi * H_DIM);
        const float4* er = (const float4*)(eemb + (size_t)ei * H_DIM);
        const float4 a = xr[lane4];
        const float4 p = pr[lane4];
        const float4 e = er[lane4];
        val.x = a.x + p.x + e.x;
        val.y = a.y + p.y + e.y;
        val.z = a.z + p.z + e.z;
        val.w = a.w + p.w + e.w;
    }
    ((float4*)out)[(size_t)frame * 64 + lane4] = val;
}

extern "C" void kernel_launch(void* const* d_in, const int* in_sizes, int n_in,
                              void* d_out, int out_size, void* d_ws, size_t ws_size,
                              hipStream_t stream) {
    const float* x     = (const float*)d_in[0];
    const float* pt    = (const float*)d_in[1];
    const float* et    = (const float*)d_in[2];
    const float* pbins = (const float*)d_in[3];
    const float* ebins = (const float*)d_in[4];
    const float* pemb  = (const float*)d_in[5];
    const float* eemb  = (const float*)d_in[6];
    const int*   dur   = (const int*)d_in[7];

    float* out = (float*)d_out;                            // 32*4096*256 f32
    float* mel_out = out + (size_t)B_SZ * MAX_LEN * H_DIM; // 32 f32 (tuple tail)

    int* pack_idx = (int*)d_ws;                            // 64 KB
    int* ph_idx   = pack_idx + B_SZ * T_PH;                // 512 KB

    prep_kernel<<<B_SZ, T_PH, 0, stream>>>(dur, pt, et, pbins, ebins,
                                           pack_idx, ph_idx, mel_out);

    const int frames = B_SZ * MAX_LEN;                     // 131072
    expand_kernel<<<frames / 4, 256, 0, stream>>>(x, pemb, eemb,
                                                  pack_idx, ph_idx, out);
}

// Round 3
// 33.181 us; speedup vs baseline: 2.0405x; 1.0401x over previous
//
#include <hip/hip_runtime.h>

#define B_SZ 32
#define T_PH 512
#define H_DIM 256
#define N_EDGES 255
#define MAX_LEN 4096

typedef float f32x4 __attribute__((ext_vector_type(4)));

// ---------------- Kernel A: scan + bin bisects + coalesced packed-frame fill ----------
// One block per batch row. frames[b][t] = ph | pi<<9 | ei<<17  (or -1 past mel_len)
__global__ void prep_kernel(const int* __restrict__ dur,
                            const float* __restrict__ pt,
                            const float* __restrict__ et,
                            const float* __restrict__ pbins,
                            const float* __restrict__ ebins,
                            int* __restrict__ frames,
                            float* __restrict__ mel_out) {
    const int b = blockIdx.x;
    const int tid = threadIdx.x;
    __shared__ int cs[T_PH];
    __shared__ int packv[T_PH];
    __shared__ float pb[N_EDGES];
    __shared__ float eb[N_EDGES];

    if (tid < N_EDGES) pb[tid] = pbins[tid];
    else if (tid >= 256 && tid < 256 + N_EDGES) eb[tid - 256] = ebins[tid - 256];

    const int d = dur[b * T_PH + tid];
    cs[tid] = d;
    __syncthreads();
#pragma unroll
    for (int off = 1; off < T_PH; off <<= 1) {
        int v = (tid >= off) ? cs[tid - off] : 0;
        __syncthreads();
        cs[tid] += v;
        __syncthreads();
    }

    // per-phoneme bin bisects (side='left'), bins in LDS
    const float pv = pt[b * T_PH + tid];
    const float ev = et[b * T_PH + tid];
    int lo = 0, hi = N_EDGES;
    while (lo < hi) { int m = (lo + hi) >> 1; if (pb[m] < pv) lo = m + 1; else hi = m; }
    const int pi = lo;
    lo = 0; hi = N_EDGES;
    while (lo < hi) { int m = (lo + hi) >> 1; if (eb[m] < ev) lo = m + 1; else hi = m; }
    const int ei = lo;
    packv[tid] = tid | (pi << 9) | (ei << 17);
    __syncthreads();

    const int mel = cs[T_PH - 1];

    // each thread resolves 8 consecutive frames: one LDS bisect + monotone walk
    const int t0 = tid * 8;
    int p = 0;
    if (t0 < mel) {
        int l = 0, h = T_PH;   // searchsorted(cs, t0, side='right')
        while (l < h) { int m = (l + h) >> 1; if (cs[m] > t0) h = m; else l = m + 1; }
        p = l;
    }
    int o[8];
#pragma unroll
    for (int j = 0; j < 8; ++j) {
        const int t = t0 + j;
        int v = -1;
        if (t < mel) {
            while (cs[p] <= t) ++p;   // monotone advance
            v = packv[p];
        }
        o[j] = v;
    }
    int4* fr = (int4*)(frames + (size_t)b * MAX_LEN);
    fr[tid * 2]     = make_int4(o[0], o[1], o[2], o[3]);
    fr[tid * 2 + 1] = make_int4(o[4], o[5], o[6], o[7]);

    if (tid == T_PH - 1) mel_out[b] = (float)mel;  // exact for < 2^24
}

// ---------------- Kernel B: single index load + gather + NT store ----------------
// 4 frames/block, 64 lanes/frame, float4 per lane
__global__ void expand_kernel(const float* __restrict__ x,
                              const float* __restrict__ pemb,
                              const float* __restrict__ eemb,
                              const int* __restrict__ frames,
                              float* __restrict__ out) {
    const int sub   = threadIdx.x >> 6;
    const int lane4 = threadIdx.x & 63;
    const int frame = blockIdx.x * 4 + sub;
    const int b = frame >> 12;

    const int pk = frames[frame];            // wave-uniform broadcast
    f32x4 val = {0.f, 0.f, 0.f, 0.f};
    if (pk >= 0) {
        const int ph = pk & 511;
        const int pi = (pk >> 9) & 255;
        const int ei = (pk >> 17) & 255;
        const f32x4* xr = (const f32x4*)(x + (size_t)(b * T_PH + ph) * H_DIM);
        const f32x4* pr = (const f32x4*)(pemb + (size_t)pi * H_DIM);
        const f32x4* er = (const f32x4*)(eemb + (size_t)ei * H_DIM);
        const f32x4 a = xr[lane4];
        const f32x4 p = pr[lane4];
        const f32x4 e = er[lane4];
        val = a + p + e;
    }
    __builtin_nontemporal_store(val, (f32x4*)out + (size_t)frame * 64 + lane4);
}

extern "C" void kernel_launch(void* const* d_in, const int* in_sizes, int n_in,
                              void* d_out, int out_size, void* d_ws, size_t ws_size,
                              hipStream_t stream) {
    const float* x     = (const float*)d_in[0];
    const float* pt    = (const float*)d_in[1];
    const float* et    = (const float*)d_in[2];
    const float* pbins = (const float*)d_in[3];
    const float* ebins = (const float*)d_in[4];
    const float* pemb  = (const float*)d_in[5];
    const float* eemb  = (const float*)d_in[6];
    const int*   dur   = (const int*)d_in[7];

    float* out = (float*)d_out;                            // 32*4096*256 f32
    float* mel_out = out + (size_t)B_SZ * MAX_LEN * H_DIM; // 32 f32 (tuple tail)

    int* frames = (int*)d_ws;                              // 512 KB packed indices

    prep_kernel<<<B_SZ, T_PH, 0, stream>>>(dur, pt, et, pbins, ebins,
                                           frames, mel_out);

    const int nframes = B_SZ * MAX_LEN;                    // 131072
    expand_kernel<<<nframes / 4, 256, 0, stream>>>(x, pemb, eemb, frames, out);
}